// Round 2
// baseline (6826.299 us; speedup 1.0000x reference)
//
#include <hip/hip_runtime.h>

// PredictorRNN: 2076 sequential GRU steps in ONE persistent kernel.
// Round-12 = round-11 logic with the ctrl handshake region RELOCATED inside
// the round-10 workspace footprint. Round-11 appended ctrl past hbuf+xext and
// grew the memset => OOB write on the 1.5MiB workspace => HSA abort (the
// bench died before any dispatch). ctrl now lives in the xext pass-7 slice
// ([8]th prediction block), which is written only at the very last pass
// boundary and NEVER read (readers use p2 = t-T_ <= 6), so the handshake
// (which completes before any exchange traffic) cannot collide with it.
//
// Device logic (unchanged from round-11):
// The per-step cross-block h broadcast is the critical path (~7465 cy/step,
// all utilizations <12%). Blocks of a group land on the SAME XCD under
// round-robin dispatch; within an XCD the L2 IS coherent. So:
//  - runtime handshake: each block reads HW_REG_XCC_ID, takes a per-XCD
//    ticket; if every XCD holds exactly 16 blocks, groups are re-formed
//    XCD-pure and a bounded self-test validates plain-store -> sc0-load
//    visibility through L2. Any anomaly => demote ALL blocks to the
//    champion MALL path (identical to round-10).
//  - pure mode: h/xext exchange via plain write-through stores + inline-asm
//    `global_load sc0` (bypass L1 only, served by XCD L2, ~250cy) instead of
//    agent-scope sc1 ops (MALL, ~600-900cy each way). Tighter poll backoff.
// Signature that pure mode engaged: WRITE_SIZE collapses 1.08GB -> <0.2GB.
// 128 blocks x 256 threads (4 waves => 512-VGPR budget; weights stay
// register-resident — 512-thread blocks cap at 256 VGPR and SPILL: round-9).

typedef __attribute__((ext_vector_type(8))) short short8;   // 8 x bf16 frag
typedef __attribute__((ext_vector_type(4))) float floatx4;

#define B_    256
#define T_    256
#define I_    64
#define H_    512
#define HZ    8
#define LPAD  520            // LDS staging pitch (ushorts), rows 16B-aligned
#define HLSZ  (16 * LPAD)    // one staging buffer (16 rows)

#define MFMA_BF16(acc, a, b) \
  acc = __builtin_amdgcn_mfma_f32_16x16x32_bf16((a), (b), (acc), 0, 0, 0)

// escalating backoff for MALL poll loops (it = retry count)
#define POLL_BACKOFF_MALL(it)                    \
  do {                                           \
    if ((it) < 2)      __builtin_amdgcn_s_sleep(1);  \
    else if ((it) < 8) __builtin_amdgcn_s_sleep(4);  \
    else               __builtin_amdgcn_s_sleep(16); \
  } while (0)
// L2 rounds are ~4x shorter: keep sleeps small to avoid overshoot
#define POLL_BACKOFF_L2(it)                      \
  do {                                           \
    if ((it) < 4)       __builtin_amdgcn_s_sleep(1); \
    else if ((it) < 12) __builtin_amdgcn_s_sleep(2); \
    else                __builtin_amdgcn_s_sleep(8); \
  } while (0)

// sc0-only load: bypass L1, served by the XCD's (coherent) L2.
#define LD64_SC0(dst, addr) \
  asm volatile("global_load_dwordx2 %0, %1, off sc0" : "=v"(dst) : "v"(addr))
// one wait for all outstanding asm loads; sched_barrier stops hipcc from
// hoisting register-only consumers above the waitcnt (guide rule #18)
#define VM_FENCE()                                       \
  do {                                                   \
    asm volatile("s_waitcnt vmcnt(0)" ::: "memory");     \
    __builtin_amdgcn_sched_barrier(0);                   \
  } while (0)

__device__ __forceinline__ float bf2f(unsigned short u) {
  union { unsigned int i; float f; } v; v.i = ((unsigned int)u) << 16; return v.f;
}
__device__ __forceinline__ unsigned short f2bf(float f) {
  union { float f; unsigned int i; } v; v.f = f;
  return (unsigned short)((v.i + 0x7FFFu + ((v.i >> 16) & 1u)) >> 16);  // RNE
}
__device__ __forceinline__ short8 ld8_f32_to_bf16(const float* p) {
  short8 r;
#pragma unroll
  for (int e = 0; e < 8; ++e) r[e] = (short)f2bf(p[e]);
  return r;
}
__device__ __forceinline__ float sigm(float xx) {
  return __builtin_amdgcn_rcpf(1.f + __expf(-xx));
}
__device__ __forceinline__ float tanh_fast(float xx) {
  float e = __expf(2.f * xx);                 // +inf -> 1, 0 -> -1
  return 1.f - 2.f * __builtin_amdgcn_rcpf(e + 1.f);
}
// relaxed agent-scope atomics (lower to global ops with L1/L2 bypass -> MALL)
__device__ __forceinline__ unsigned long long ald64(const unsigned int* p) {
  return __hip_atomic_load((const unsigned long long*)p, __ATOMIC_RELAXED,
                           __HIP_MEMORY_SCOPE_AGENT);
}
__device__ __forceinline__ unsigned int ald32(const unsigned int* p) {
  return __hip_atomic_load(p, __ATOMIC_RELAXED, __HIP_MEMORY_SCOPE_AGENT);
}
__device__ __forceinline__ void ast32(unsigned int* p, unsigned int v) {
  __hip_atomic_store(p, v, __ATOMIC_RELAXED, __HIP_MEMORY_SCOPE_AGENT);
}
// plain store (workgroup-scope atomic => global_store, no sc bits). CDNA L1
// is write-through, so this lands in the XCD L2 where sc0 loads see it.
__device__ __forceinline__ void st32_wg(unsigned int* p, unsigned int v) {
  __hip_atomic_store(p, v, __ATOMIC_RELAXED, __HIP_MEMORY_SCOPE_WORKGROUP);
}

// ---- tagged h staging: poll 16x u64 per thread, then write to LDS ----
template <bool PURE>
__device__ __forceinline__ void stage_h16(unsigned short* hl,
                                          const unsigned int* hb,
                                          unsigned int want, int tid) {
  unsigned long long v[16];
#pragma unroll
  for (int i = 0; i < 16; ++i) {
    int c = tid + (i << 8), r = c >> 8, o = (c & 255) << 1;
    if constexpr (PURE) { LD64_SC0(v[i], hb + (size_t)r * H_ + o); }
    else                { v[i] = ald64(hb + (size_t)r * H_ + o); }
  }
  if constexpr (PURE) VM_FENCE();
  int it = 0;
  for (;;) {
    bool all = true;
#pragma unroll
    for (int i = 0; i < 16; ++i) {
      unsigned int w0 = (unsigned int)v[i];
      unsigned int w1 = (unsigned int)(v[i] >> 32);
      if (((w0 >> 16) != want) || ((w1 >> 16) != want)) {
        all = false;
        int c = tid + (i << 8), r = c >> 8, o = (c & 255) << 1;
        if constexpr (PURE) { LD64_SC0(v[i], hb + (size_t)r * H_ + o); }
        else                { v[i] = ald64(hb + (size_t)r * H_ + o); }
      }
    }
    if (all) break;
    if constexpr (PURE) POLL_BACKOFF_L2(it); else POLL_BACKOFF_MALL(it);
    ++it;
    if constexpr (PURE) VM_FENCE();   // sleep overlapped the reload latency
  }
#pragma unroll
  for (int i = 0; i < 16; ++i) {
    int c = tid + (i << 8), r = c >> 8, o = (c & 255) << 1;
    unsigned int w0 = (unsigned int)v[i];
    unsigned int w1 = (unsigned int)(v[i] >> 32);
    *(unsigned int*)&hl[r * LPAD + o] = (w0 & 0xffffu) | (w1 << 16);
  }
}

template <bool PURE>
__device__ __forceinline__ void body(
    const float* __restrict__ x, const float* __restrict__ w_ih,
    const float* __restrict__ w_hh, const float* __restrict__ b_ih,
    const float* __restrict__ b_hh, const float* __restrict__ fc_w,
    const float* __restrict__ fc_b, float* __restrict__ out,
    unsigned int* __restrict__ hbuf, unsigned int* __restrict__ xext,
    unsigned short* hls, int grp, int slot) {
  const int tid  = threadIdx.x;
  const int wave = tid >> 6;                  // 0..3
  const int lane = tid & 63;
  const int ju   = (slot << 2) | wave;        // 0..31 j-tile unit in group
  const int n16  = lane & 15;
  const int quad = lane >> 4;
  const int jg   = ju * 16 + n16;             // output column j (0..511)
  const int rowbase = grp * 16;               // 16 batch rows per group

  // ---- one-time: fp32 weights -> bf16 B-fragments in registers ----
  // B-frag (16x16x32): lane holds B[k = kc*32 + quad*8 + e][n = lane&15];
  // B[k][j] = W[j][k] => weight row (gate*512+jg), cols kc*32+quad*8.
  short8 wR[18], wZ[18], wHN[16], wXN[2];
  {
    const int koff = quad * 8;
    const float* whr = w_hh + (size_t)(0 * H_ + jg) * H_ + koff;
    const float* whz = w_hh + (size_t)(1 * H_ + jg) * H_ + koff;
    const float* whn = w_hh + (size_t)(2 * H_ + jg) * H_ + koff;
#pragma unroll
    for (int kc = 0; kc < 16; ++kc) {
      wR[kc]  = ld8_f32_to_bf16(whr + kc * 32);
      wZ[kc]  = ld8_f32_to_bf16(whz + kc * 32);
      wHN[kc] = ld8_f32_to_bf16(whn + kc * 32);
    }
    const float* wir = w_ih + (size_t)(0 * H_ + jg) * I_ + koff;
    const float* wiz = w_ih + (size_t)(1 * H_ + jg) * I_ + koff;
    const float* win = w_ih + (size_t)(2 * H_ + jg) * I_ + koff;
#pragma unroll
    for (int kc = 0; kc < 2; ++kc) {
      wR[16 + kc] = ld8_f32_to_bf16(wir + kc * 32);
      wZ[16 + kc] = ld8_f32_to_bf16(wiz + kc * 32);
      wXN[kc]     = ld8_f32_to_bf16(win + kc * 32);
    }
  }
  const float brc = b_ih[jg]          + b_hh[jg];
  const float bzc = b_ih[H_ + jg]     + b_hh[H_ + jg];
  const float bxn = b_ih[2 * H_ + jg];
  const float bhn = b_hh[2 * H_ + jg];

  float hloc[4] = {0.f, 0.f, 0.f, 0.f};   // fp32 recurrent carry (C/D layout)

  int s = 0;
  for (int p = 0; p < HZ; ++p) {
    const int Tp = T_ + p;
    for (int t = 0; t < Tp; ++t) {
      // ---- x A-fragment (prefetch overlaps the h spin) ----
      short8 xaf0, xaf1;
      if (t < T_) {
        const float* xs = x + ((size_t)(rowbase + n16) * T_ + t) * I_ + quad * 8;
        xaf0 = ld8_f32_to_bf16(xs);
        xaf1 = ld8_f32_to_bf16(xs + 32);
      }
      // ---- stage h^(s-1) (tagged, self-synchronizing) into LDS[s&1] ----
      unsigned short* hl = &hls[(s & 1) * HLSZ];
      if (s > 0) {
        const unsigned int* hb = hbuf + (size_t)((s + 1) & 1) * (B_ * H_) +
                                 (size_t)rowbase * H_;
        stage_h16<PURE>(hl, hb, (unsigned int)s, tid);
      } else {  // s == 0: h_prev = 0
#pragma unroll
        for (int i = 0; i < 16; ++i) {
          int c = tid + (i << 8), r = c >> 8, o = (c & 255) << 1;
          *(unsigned int*)&hl[r * LPAD + o] = 0u;
        }
      }
      // ---- xext A-fragment for appended timesteps (tagged) ----
      if (t >= T_) {
        const int p2 = t - T_;
        const unsigned int wantx = (unsigned int)(p2 + 1);
        const unsigned int* xb =
            xext + ((size_t)p2 * B_ + rowbase + n16) * I_;
        unsigned long long u[8];
#pragma unroll
        for (int k = 0; k < 8; ++k) {
          int off = (k < 4) ? (quad * 8 + 2 * k) : (32 + quad * 8 + 2 * (k - 4));
          if constexpr (PURE) { LD64_SC0(u[k], xb + off); }
          else                { u[k] = ald64(xb + off); }
        }
        if constexpr (PURE) VM_FENCE();
        int it = 0;
        for (;;) {
          bool all = true;
#pragma unroll
          for (int k = 0; k < 8; ++k) {
            unsigned int w0 = (unsigned int)u[k];
            unsigned int w1 = (unsigned int)(u[k] >> 32);
            if (((w0 >> 16) != wantx) || ((w1 >> 16) != wantx)) {
              all = false;
              int off = (k < 4) ? (quad * 8 + 2 * k)
                                : (32 + quad * 8 + 2 * (k - 4));
              if constexpr (PURE) { LD64_SC0(u[k], xb + off); }
              else                { u[k] = ald64(xb + off); }
            }
          }
          if (all) break;
          if constexpr (PURE) POLL_BACKOFF_L2(it); else POLL_BACKOFF_MALL(it);
          ++it;
          if constexpr (PURE) VM_FENCE();
        }
#pragma unroll
        for (int k = 0; k < 4; ++k) {
          xaf0[2 * k]     = (short)(unsigned short)u[k];
          xaf0[2 * k + 1] = (short)(unsigned short)(u[k] >> 32);
          xaf1[2 * k]     = (short)(unsigned short)u[4 + k];
          xaf1[2 * k + 1] = (short)(unsigned short)(u[4 + k] >> 32);
        }
      }
      __syncthreads();   // staging visible; also protects LDS parity reuse
      short8 haf[16];
#pragma unroll
      for (int kc = 0; kc < 16; ++kc)
        haf[kc] = *(const short8*)&hl[n16 * LPAD + kc * 32 + quad * 8];

      floatx4 aR = {0.f, 0.f, 0.f, 0.f};
      floatx4 aZ = {0.f, 0.f, 0.f, 0.f};
      floatx4 aN = {0.f, 0.f, 0.f, 0.f};
      floatx4 aX = {0.f, 0.f, 0.f, 0.f};
#pragma unroll
      for (int kc = 0; kc < 16; ++kc) {
        MFMA_BF16(aR, haf[kc], wR[kc]);
        MFMA_BF16(aZ, haf[kc], wZ[kc]);
        MFMA_BF16(aN, haf[kc], wHN[kc]);
      }
      MFMA_BF16(aR, xaf0, wR[16]);  MFMA_BF16(aR, xaf1, wR[17]);
      MFMA_BF16(aZ, xaf0, wZ[16]);  MFMA_BF16(aZ, xaf1, wZ[17]);
      MFMA_BF16(aX, xaf0, wXN[0]);  MFMA_BF16(aX, xaf1, wXN[1]);

      // ---- epilogue: tagged scatter stores, fire-and-forget ----
      // (lanes n16=0..15 of a quad hit consecutive j -> 64B-line coalesced)
      unsigned int* hd = hbuf + (size_t)(s & 1) * (B_ * H_);
      const unsigned int tg = ((unsigned int)(s + 1)) << 16;
#pragma unroll
      for (int i = 0; i < 4; ++i) {
        float rv = sigm(aR[i] + brc);
        float zv = sigm(aZ[i] + bzc);
        float nv = tanh_fast(aX[i] + bxn + rv * (aN[i] + bhn));
        float hn = (1.f - zv) * nv + zv * hloc[i];
        hloc[i]  = hn;
        unsigned int* dst = &hd[(size_t)(rowbase + quad * 4 + i) * H_ + jg];
        unsigned int val = tg | (unsigned int)f2bf(hn);
        if constexpr (PURE) st32_wg(dst, val); else ast32(dst, val);
      }
      ++s;
    }
    // ---- pass boundary: pred_p = h_final @ fc_w^T + fc_b ----
    {
      unsigned short* hl = &hls[(s & 1) * HLSZ];
      const unsigned int* hb = hbuf + (size_t)((s + 1) & 1) * (B_ * H_) +
                               (size_t)rowbase * H_;
      stage_h16<PURE>(hl, hb, (unsigned int)s, tid);
      __syncthreads();
      const int mm  = lane & 15;
      const int sub = lane >> 4;
#pragma unroll
      for (int cc = 0; cc < 2; ++cc) {
        const int c = ju * 2 + cc;
        const unsigned short* hrow = &hl[mm * LPAD + sub * 128];
        const float* wrow = fc_w + (size_t)c * H_ + sub * 128;
        float acc = 0.f;
#pragma unroll
        for (int kk = 0; kk < 128; kk += 8) {
          short8 hv = *(const short8*)(hrow + kk);
#pragma unroll
          for (int e = 0; e < 8; ++e)
            acc = fmaf(bf2f((unsigned short)hv[e]), wrow[kk + e], acc);
        }
        acc += __shfl_xor(acc, 16, 64);
        acc += __shfl_xor(acc, 32, 64);
        if (sub == 0) {
          float val = acc + fc_b[c];
          out[((size_t)(rowbase + mm) * HZ + p) * I_ + c] = val;   // fp32
          unsigned int* xd = &xext[((size_t)p * B_ + rowbase + mm) * I_ + c];
          unsigned int xv = (((unsigned int)(p + 1)) << 16) |
                            (unsigned int)f2bf(val);
          if constexpr (PURE) st32_wg(xd, xv); else ast32(xd, xv);
        }
      }
      __syncthreads();   // fc reads done before next pass restages LDS[s&1]
    }
  }
}

extern "C" __global__ void __launch_bounds__(256, 1)
gru_chain(const float* __restrict__ x,       // [256][256][64] fp32
          const float* __restrict__ w_ih,    // [1536][64]   fp32
          const float* __restrict__ w_hh,    // [1536][512]  fp32
          const float* __restrict__ b_ih,    // [1536]       fp32
          const float* __restrict__ b_hh,    // [1536]       fp32
          const float* __restrict__ fc_w,    // [64][512]    fp32
          const float* __restrict__ fc_b,    // [64]         fp32
          float* __restrict__ out,           // [256][8][64] fp32
          unsigned int* __restrict__ hbuf,   // ws: [2][256][512] tagged u32
          unsigned int* __restrict__ xext,   // ws: [8][256][64]  tagged u32
          unsigned int* __restrict__ ctrl)   // ws: handshake (xext p=7 slice)
{
  __shared__ __align__(16) unsigned short hls[2 * HLSZ];  // double-buffered
  __shared__ int s_asn;

  // ---- one-time handshake: discover XCD placement, form pure groups ----
  // ctrl lives in the xext pass-7 slice (written only at the LAST pass
  // boundary, never read) => zero extra ws footprint, covered by the memset.
  // ctrl[0..7]=per-XCD tickets, [9]=self-test ok count, [10]=done count,
  // [16..143]=self-test slots. All agent-scope (MALL) => placement-agnostic.
  if (threadIdx.x == 0) {
    unsigned int xcd;
    asm volatile("s_getreg_b32 %0, hwreg(HW_REG_XCC_ID)" : "=s"(xcd));
    xcd &= 7u;
    unsigned int tk = __hip_atomic_fetch_add(&ctrl[xcd], 1u, __ATOMIC_RELAXED,
                                             __HIP_MEMORY_SCOPE_AGENT);
    unsigned int c[8];
    for (;;) {                      // wait until all 128 blocks ticketed
      unsigned int sum = 0;
#pragma unroll
      for (int i = 0; i < 8; ++i) { c[i] = ald32(&ctrl[i]); sum += c[i]; }
      if (sum >= 128u) break;
      __builtin_amdgcn_s_sleep(8);
    }
    int pure = 1;
#pragma unroll
    for (int i = 0; i < 8; ++i) pure &= (c[i] == 16u);   // balanced RR only
    int grp, slot;
    if (pure) { grp = (int)(xcd * 2u + (tk >> 3)); slot = (int)(tk & 7u); }
    else      { grp = (int)(blockIdx.x & 15u);     slot = (int)(blockIdx.x >> 4); }
    if (pure) {
      // bounded self-test of plain-store -> sc0-load visibility within the
      // group (exact main-loop pattern). Timeout => demote grid to MALL.
      unsigned int* gs = ctrl + 16;
      st32_wg(&gs[grp * 8 + slot], 1u);
      int ok = 1;
      for (int k = 0; k < 8 && ok; ++k) {
        unsigned int vv = 0;
        for (int sp = 0; sp < 512; ++sp) {
          asm volatile("global_load_dword %0, %1, off sc0\n\t"
                       "s_waitcnt vmcnt(0)"
                       : "=v"(vv) : "v"(gs + grp * 8 + k) : "memory");
          if (vv) break;
          __builtin_amdgcn_s_sleep(1);
        }
        if (!vv) ok = 0;
      }
      __hip_atomic_fetch_add(&ctrl[9], (unsigned int)ok, __ATOMIC_RELAXED,
                             __HIP_MEMORY_SCOPE_AGENT);
      __hip_atomic_fetch_add(&ctrl[10], 1u, __ATOMIC_RELAXED,
                             __HIP_MEMORY_SCOPE_AGENT);
      while (ald32(&ctrl[10]) < 128u) __builtin_amdgcn_s_sleep(4);
      pure = (ald32(&ctrl[9]) == 128u) ? 1 : 0;
      if (!pure) { grp = (int)(blockIdx.x & 15u); slot = (int)(blockIdx.x >> 4); }
    }
    s_asn = (grp << 5) | (slot << 1) | pure;
  }
  __syncthreads();
  const int asn  = s_asn;
  const int grp  = asn >> 5;
  const int slot = (asn >> 1) & 15;

  if (asn & 1)
    body<true>(x, w_ih, w_hh, b_ih, b_hh, fc_w, fc_b, out, hbuf, xext,
               hls, grp, slot);
  else
    body<false>(x, w_ih, w_hh, b_ih, b_hh, fc_w, fc_b, out, hbuf, xext,
                hls, grp, slot);
}

extern "C" void kernel_launch(void* const* d_in, const int* in_sizes, int n_in,
                              void* d_out, int out_size, void* d_ws, size_t ws_size,
                              hipStream_t stream) {
  const float* x    = (const float*)d_in[0];
  const float* w_ih = (const float*)d_in[1];
  const float* w_hh = (const float*)d_in[2];
  const float* b_ih = (const float*)d_in[3];
  const float* b_hh = (const float*)d_in[4];
  const float* fc_w = (const float*)d_in[5];
  const float* fc_b = (const float*)d_in[6];
  float* out = (float*)d_out;

  unsigned char* ws = (unsigned char*)d_ws;
  const size_t hbuf_b = (size_t)2 * B_ * H_ * 4;   // 1 MiB (tagged u32)
  const size_t xext_b = (size_t)HZ * B_ * I_ * 4;  // 512 KiB (tagged u32)
  unsigned int* hbuf = (unsigned int*)ws;
  unsigned int* xext = (unsigned int*)(ws + hbuf_b);
  // handshake scratch INSIDE the footprint: xext pass-7 slice (never read;
  // written only at the final pass boundary, long after the handshake).
  unsigned int* ctrl = xext + (size_t)(HZ - 1) * B_ * I_;

  // zero tags (0 = invalid; the harness's 0xAA poison is also invalid).
  // Same footprint as round-10 — NO extra bytes past hbuf+xext.
  hipMemsetAsync(d_ws, 0, hbuf_b + xext_b, stream);

  // 128 blocks on 256 CUs — all co-resident (self-sync safe)
  gru_chain<<<dim3(128), dim3(256), 0, stream>>>(
      x, w_ih, w_hh, b_ih, b_hh, fc_w, fc_b, out, hbuf, xext, ctrl);
}

// Round 3
// 6415.881 us; speedup vs baseline: 1.0640x; 1.0640x over previous
//
#include <hip/hip_runtime.h>

// PredictorRNN: 2076 sequential GRU steps in ONE persistent kernel.
// Round-13 = round-10 champion (handshake/L2-pure of r11/r12 fully reverted:
// it cost +370us and its diagnostic was ambiguous) + CHEAP-CHANNEL POLLING.
// Theory: 7465 cy/step vs ~1100 cy compute+stage. The champion poll re-loads
// ALL 16 u64/thread per retry = 32KB/block/retry => ~4MB/grid poll rounds
// hammering MALL (invisible in FETCH/WRITE - MALL-resident), plus s_sleep(16)
// (~1024cy) overshoot. Fix: speculative full sweep once; while not ready,
// poll only 8B/thread of row 15 (last-issued store of the producer burst)
// with tight 64-128cy backoff; when the sentinel row is tagged, re-fetch the
// remaining stale words. Full per-word tag verification retained => correct
// under ANY arrival order; the sentinel is only a traffic heuristic.
// TAGGED h-exchange: every h element stored as (step_tag<<16|bf16) u32 via
// relaxed agent-scope atomics (MALL-coherent). Consumers poll the data
// itself (detection == arrival; no flags, no fences).
// 128 blocks x 256 threads (4 waves => 512-VGPR budget; weights stay
// register-resident — 512-thread blocks cap at 256 VGPR and SPILL: round-9).

typedef __attribute__((ext_vector_type(8))) short short8;   // 8 x bf16 frag
typedef __attribute__((ext_vector_type(4))) float floatx4;

#define B_    256
#define T_    256
#define I_    64
#define H_    512
#define HZ    8
#define LPAD  520            // LDS staging pitch (ushorts), rows 16B-aligned
#define HLSZ  (16 * LPAD)    // one staging buffer (16 rows)

#define MFMA_BF16(acc, a, b) \
  acc = __builtin_amdgcn_mfma_f32_16x16x32_bf16((a), (b), (acc), 0, 0, 0)

// escalating backoff for wide (32KB-class) poll loops — champion tuning
#define POLL_BACKOFF(it)                         \
  do {                                           \
    if ((it) < 2)      __builtin_amdgcn_s_sleep(1);  \
    else if ((it) < 8) __builtin_amdgcn_s_sleep(4);  \
    else               __builtin_amdgcn_s_sleep(16); \
  } while (0)
// tight backoff for the 8B/thread sentinel channel (cheap => poll fast;
// small quanta kill the up-to-1024cy overshoot of the wide backoff)
#define POLL_TIGHT(it)                           \
  do {                                           \
    if ((it) < 4)       __builtin_amdgcn_s_sleep(1); \
    else if ((it) < 16) __builtin_amdgcn_s_sleep(2); \
    else                __builtin_amdgcn_s_sleep(8); \
  } while (0)

__device__ __forceinline__ float bf2f(unsigned short u) {
  union { unsigned int i; float f; } v; v.i = ((unsigned int)u) << 16; return v.f;
}
__device__ __forceinline__ unsigned short f2bf(float f) {
  union { float f; unsigned int i; } v; v.f = f;
  return (unsigned short)((v.i + 0x7FFFu + ((v.i >> 16) & 1u)) >> 16);  // RNE
}
__device__ __forceinline__ short8 ld8_f32_to_bf16(const float* p) {
  short8 r;
#pragma unroll
  for (int e = 0; e < 8; ++e) r[e] = (short)f2bf(p[e]);
  return r;
}
__device__ __forceinline__ float sigm(float xx) {
  return __builtin_amdgcn_rcpf(1.f + __expf(-xx));
}
__device__ __forceinline__ float tanh_fast(float xx) {
  float e = __expf(2.f * xx);                 // +inf -> 1, 0 -> -1
  return 1.f - 2.f * __builtin_amdgcn_rcpf(e + 1.f);
}
// relaxed agent-scope atomics (lower to global ops with L1/L2 bypass -> MALL)
__device__ __forceinline__ unsigned long long ald64(const unsigned int* p) {
  return __hip_atomic_load((const unsigned long long*)p, __ATOMIC_RELAXED,
                           __HIP_MEMORY_SCOPE_AGENT);
}
__device__ __forceinline__ void ast32(unsigned int* p, unsigned int v) {
  __hip_atomic_store(p, v, __ATOMIC_RELAXED, __HIP_MEMORY_SCOPE_AGENT);
}

// ---- tagged h staging with cheap-channel polling ----
// thread's slice: row i (i=0..15), 8B at word offset 2*tid within the row.
// 1) speculative full sweep (16 x 8B);
// 2) while row-15 sentinel not tagged: poll ONLY it (8B) with tight backoff;
// 3) sentinel tagged: re-fetch remaining stale words; re-verify everything.
__device__ __forceinline__ void stage_h16(unsigned short* hl,
                                          const unsigned int* hb,
                                          unsigned int want, int tid) {
  unsigned long long v[16];
#pragma unroll
  for (int i = 0; i < 16; ++i)
    v[i] = ald64(hb + (size_t)i * H_ + 2 * tid);
  int it = 0;
  for (;;) {
    bool all = true, ok15 = true;
#pragma unroll
    for (int i = 0; i < 16; ++i) {
      unsigned int w0 = (unsigned int)v[i];
      unsigned int w1 = (unsigned int)(v[i] >> 32);
      if (((w0 >> 16) != want) || ((w1 >> 16) != want)) {
        all = false;
        if (i == 15) ok15 = false;
      }
    }
    if (all) break;
    if (!ok15) {                       // cheap wait channel: 8B/thread
      POLL_TIGHT(it); ++it;
      v[15] = ald64(hb + (size_t)15 * H_ + 2 * tid);
    } else {                           // sentinel ready: fetch stragglers
#pragma unroll
      for (int i = 0; i < 15; ++i) {
        unsigned int w0 = (unsigned int)v[i];
        unsigned int w1 = (unsigned int)(v[i] >> 32);
        if (((w0 >> 16) != want) || ((w1 >> 16) != want))
          v[i] = ald64(hb + (size_t)i * H_ + 2 * tid);
      }
      __builtin_amdgcn_s_sleep(1);
    }
  }
#pragma unroll
  for (int i = 0; i < 16; ++i) {
    unsigned int w0 = (unsigned int)v[i];
    unsigned int w1 = (unsigned int)(v[i] >> 32);
    *(unsigned int*)&hl[i * LPAD + 2 * tid] = (w0 & 0xffffu) | (w1 << 16);
  }
}

extern "C" __global__ void __launch_bounds__(256, 1)
gru_chain(const float* __restrict__ x,       // [256][256][64] fp32
          const float* __restrict__ w_ih,    // [1536][64]   fp32
          const float* __restrict__ w_hh,    // [1536][512]  fp32
          const float* __restrict__ b_ih,    // [1536]       fp32
          const float* __restrict__ b_hh,    // [1536]       fp32
          const float* __restrict__ fc_w,    // [64][512]    fp32
          const float* __restrict__ fc_b,    // [64]         fp32
          float* __restrict__ out,           // [256][8][64] fp32
          unsigned int* __restrict__ hbuf,   // ws: [2][256][512] tagged u32
          unsigned int* __restrict__ xext)   // ws: [8][256][64]  tagged u32
{
  const int tid  = threadIdx.x;
  const int wave = tid >> 6;                  // 0..3
  const int lane = tid & 63;
  const int bx   = blockIdx.x;                // 0..127
  const int grp  = bx & 15;                   // 16 groups x 8 blocks
  const int ju   = ((bx >> 4) << 2) | wave;   // 0..31 j-tile unit in group
  const int n16  = lane & 15;
  const int quad = lane >> 4;
  const int jg   = ju * 16 + n16;             // output column j (0..511)
  const int rowbase = grp * 16;               // 16 batch rows per group

  __shared__ __align__(16) unsigned short hls[2 * HLSZ];  // double-buffered

  // ---- one-time: fp32 weights -> bf16 B-fragments in registers ----
  // B-frag (16x16x32): lane holds B[k = kc*32 + quad*8 + e][n = lane&15];
  // B[k][j] = W[j][k] => weight row (gate*512+jg), cols kc*32+quad*8.
  short8 wR[18], wZ[18], wHN[16], wXN[2];
  {
    const int koff = quad * 8;
    const float* whr = w_hh + (size_t)(0 * H_ + jg) * H_ + koff;
    const float* whz = w_hh + (size_t)(1 * H_ + jg) * H_ + koff;
    const float* whn = w_hh + (size_t)(2 * H_ + jg) * H_ + koff;
#pragma unroll
    for (int kc = 0; kc < 16; ++kc) {
      wR[kc]  = ld8_f32_to_bf16(whr + kc * 32);
      wZ[kc]  = ld8_f32_to_bf16(whz + kc * 32);
      wHN[kc] = ld8_f32_to_bf16(whn + kc * 32);
    }
    const float* wir = w_ih + (size_t)(0 * H_ + jg) * I_ + koff;
    const float* wiz = w_ih + (size_t)(1 * H_ + jg) * I_ + koff;
    const float* win = w_ih + (size_t)(2 * H_ + jg) * I_ + koff;
#pragma unroll
    for (int kc = 0; kc < 2; ++kc) {
      wR[16 + kc] = ld8_f32_to_bf16(wir + kc * 32);
      wZ[16 + kc] = ld8_f32_to_bf16(wiz + kc * 32);
      wXN[kc]     = ld8_f32_to_bf16(win + kc * 32);
    }
  }
  const float brc = b_ih[jg]          + b_hh[jg];
  const float bzc = b_ih[H_ + jg]     + b_hh[H_ + jg];
  const float bxn = b_ih[2 * H_ + jg];
  const float bhn = b_hh[2 * H_ + jg];

  float hloc[4] = {0.f, 0.f, 0.f, 0.f};   // fp32 recurrent carry (C/D layout)

  int s = 0;
  for (int p = 0; p < HZ; ++p) {
    const int Tp = T_ + p;
    for (int t = 0; t < Tp; ++t) {
      // ---- x A-fragment (prefetch overlaps the h spin) ----
      short8 xaf0, xaf1;
      if (t < T_) {
        const float* xs = x + ((size_t)(rowbase + n16) * T_ + t) * I_ + quad * 8;
        xaf0 = ld8_f32_to_bf16(xs);
        xaf1 = ld8_f32_to_bf16(xs + 32);
      }
      // ---- stage h^(s-1) (tagged, self-synchronizing) into LDS[s&1] ----
      unsigned short* hl = &hls[(s & 1) * HLSZ];
      if (s > 0) {
        const unsigned int* hb = hbuf + (size_t)((s + 1) & 1) * (B_ * H_) +
                                 (size_t)rowbase * H_;
        stage_h16(hl, hb, (unsigned int)s, tid);
      } else {  // s == 0: h_prev = 0
#pragma unroll
        for (int i = 0; i < 16; ++i)
          *(unsigned int*)&hl[i * LPAD + 2 * tid] = 0u;
      }
      // ---- xext A-fragment for appended timesteps (tagged) ----
      if (t >= T_) {
        const int p2 = t - T_;
        const unsigned int wantx = (unsigned int)(p2 + 1);
        const unsigned int* xb =
            xext + ((size_t)p2 * B_ + rowbase + n16) * I_;
        unsigned long long u[8];
#pragma unroll
        for (int k = 0; k < 8; ++k) {
          int off = (k < 4) ? (quad * 8 + 2 * k) : (32 + quad * 8 + 2 * (k - 4));
          u[k] = ald64(xb + off);
        }
        int it = 0;
        for (;;) {
          bool all = true;
#pragma unroll
          for (int k = 0; k < 8; ++k) {
            unsigned int w0 = (unsigned int)u[k];
            unsigned int w1 = (unsigned int)(u[k] >> 32);
            if (((w0 >> 16) != wantx) || ((w1 >> 16) != wantx)) {
              all = false;
              int off = (k < 4) ? (quad * 8 + 2 * k)
                                : (32 + quad * 8 + 2 * (k - 4));
              u[k] = ald64(xb + off);
            }
          }
          if (all) break;
          POLL_BACKOFF(it);
          ++it;
        }
#pragma unroll
        for (int k = 0; k < 4; ++k) {
          xaf0[2 * k]     = (short)(unsigned short)u[k];
          xaf0[2 * k + 1] = (short)(unsigned short)(u[k] >> 32);
          xaf1[2 * k]     = (short)(unsigned short)u[4 + k];
          xaf1[2 * k + 1] = (short)(unsigned short)(u[4 + k] >> 32);
        }
      }
      __syncthreads();   // staging visible; also protects LDS parity reuse
      short8 haf[16];
#pragma unroll
      for (int kc = 0; kc < 16; ++kc)
        haf[kc] = *(const short8*)&hl[n16 * LPAD + kc * 32 + quad * 8];

      floatx4 aR = {0.f, 0.f, 0.f, 0.f};
      floatx4 aZ = {0.f, 0.f, 0.f, 0.f};
      floatx4 aN = {0.f, 0.f, 0.f, 0.f};
      floatx4 aX = {0.f, 0.f, 0.f, 0.f};
#pragma unroll
      for (int kc = 0; kc < 16; ++kc) {
        MFMA_BF16(aR, haf[kc], wR[kc]);
        MFMA_BF16(aZ, haf[kc], wZ[kc]);
        MFMA_BF16(aN, haf[kc], wHN[kc]);
      }
      MFMA_BF16(aR, xaf0, wR[16]);  MFMA_BF16(aR, xaf1, wR[17]);
      MFMA_BF16(aZ, xaf0, wZ[16]);  MFMA_BF16(aZ, xaf1, wZ[17]);
      MFMA_BF16(aX, xaf0, wXN[0]);  MFMA_BF16(aX, xaf1, wXN[1]);

      // ---- epilogue: tagged scatter stores, fire-and-forget ----
      // (lanes n16=0..15 of a quad hit consecutive j -> 64B-line coalesced)
      unsigned int* hd = hbuf + (size_t)(s & 1) * (B_ * H_);
      const unsigned int tg = ((unsigned int)(s + 1)) << 16;
#pragma unroll
      for (int i = 0; i < 4; ++i) {
        float rv = sigm(aR[i] + brc);
        float zv = sigm(aZ[i] + bzc);
        float nv = tanh_fast(aX[i] + bxn + rv * (aN[i] + bhn));
        float hn = (1.f - zv) * nv + zv * hloc[i];
        hloc[i]  = hn;
        ast32(&hd[(size_t)(rowbase + quad * 4 + i) * H_ + jg],
              tg | (unsigned int)f2bf(hn));
      }
      ++s;
    }
    // ---- pass boundary: pred_p = h_final @ fc_w^T + fc_b ----
    {
      unsigned short* hl = &hls[(s & 1) * HLSZ];
      const unsigned int* hb = hbuf + (size_t)((s + 1) & 1) * (B_ * H_) +
                               (size_t)rowbase * H_;
      stage_h16(hl, hb, (unsigned int)s, tid);
      __syncthreads();
      const int mm  = lane & 15;
      const int sub = lane >> 4;
#pragma unroll
      for (int cc = 0; cc < 2; ++cc) {
        const int c = ju * 2 + cc;
        const unsigned short* hrow = &hl[mm * LPAD + sub * 128];
        const float* wrow = fc_w + (size_t)c * H_ + sub * 128;
        float acc = 0.f;
#pragma unroll
        for (int kk = 0; kk < 128; kk += 8) {
          short8 hv = *(const short8*)(hrow + kk);
#pragma unroll
          for (int e = 0; e < 8; ++e)
            acc = fmaf(bf2f((unsigned short)hv[e]), wrow[kk + e], acc);
        }
        acc += __shfl_xor(acc, 16, 64);
        acc += __shfl_xor(acc, 32, 64);
        if (sub == 0) {
          float val = acc + fc_b[c];
          out[((size_t)(rowbase + mm) * HZ + p) * I_ + c] = val;   // fp32
          ast32(&xext[((size_t)p * B_ + rowbase + mm) * I_ + c],
                (((unsigned int)(p + 1)) << 16) | (unsigned int)f2bf(val));
        }
      }
      __syncthreads();   // fc reads done before next pass restages LDS[s&1]
    }
  }
}

extern "C" void kernel_launch(void* const* d_in, const int* in_sizes, int n_in,
                              void* d_out, int out_size, void* d_ws, size_t ws_size,
                              hipStream_t stream) {
  const float* x    = (const float*)d_in[0];
  const float* w_ih = (const float*)d_in[1];
  const float* w_hh = (const float*)d_in[2];
  const float* b_ih = (const float*)d_in[3];
  const float* b_hh = (const float*)d_in[4];
  const float* fc_w = (const float*)d_in[5];
  const float* fc_b = (const float*)d_in[6];
  float* out = (float*)d_out;

  unsigned char* ws = (unsigned char*)d_ws;
  const size_t hbuf_b = (size_t)2 * B_ * H_ * 4;   // 1 MiB (tagged u32)
  const size_t xext_b = (size_t)HZ * B_ * I_ * 4;  // 512 KiB (tagged u32)
  unsigned int* hbuf = (unsigned int*)ws;
  unsigned int* xext = (unsigned int*)(ws + hbuf_b);

  // zero tags (0 = invalid; the harness's 0xAA poison is also invalid)
  hipMemsetAsync(d_ws, 0, hbuf_b + xext_b, stream);

  // 128 blocks on 256 CUs — all co-resident (self-sync safe)
  gru_chain<<<dim3(128), dim3(256), 0, stream>>>(
      x, w_ih, w_hh, b_ih, b_hh, fc_w, fc_b, out, hbuf, xext);
}